// Round 4
// baseline (533.433 us; speedup 1.0000x reference)
//
#include <hip/hip_runtime.h>
#include <math.h>

// Problem constants (match reference)
constexpr int B    = 4;
constexpr int N    = 32768;   // 2^15
constexpr int K    = 16;
constexpr int CIN  = 32;
constexpr int H    = 32;
constexpr int COUT = 32;
constexpr int NODES = B * N;          // 131072 = 512*256
constexpr int E      = B * N * K;     // 2097152 edges
constexpr int NBLK  = NODES / 256;    // 512 (histogram blocks / scan width)

// ---------------------------------------------------------------------------
// Kernel 1: fc1 + fold grid_weight and gaussian normalizer into hh[node][h]
//   hh[node,h] = coef[h] * gw[node] * (sum_c x[b,c,n]*W1[h,c] + b1[h])
//   coef[h] = sqrt((bw[h]/pi)^3)
// ---------------------------------------------------------------------------
__global__ __launch_bounds__(256) void k_fc1(const float* __restrict__ x,
                                             const float* __restrict__ grid_weight,
                                             const float* __restrict__ W1,
                                             const float* __restrict__ b1,
                                             const float* __restrict__ baseweight,
                                             float* __restrict__ hh)
{
    __shared__ float sW1[H * CIN];
    __shared__ float sb1[H];
    __shared__ float scoef[H];
    const int tid = threadIdx.x;
    for (int i = tid; i < H * CIN; i += 256) sW1[i] = W1[i];
    if (tid < H) {
        sb1[tid] = b1[tid];
        float t = baseweight[tid] * (float)(1.0 / M_PI);
        scoef[tid] = t * sqrtf(t);           // (bw/pi)^1.5 == sqrt((bw/pi)^3)
    }
    __syncthreads();

    const int node = blockIdx.x * 256 + tid;  // [0, NODES)
    const int b = node >> 15;                 // node / N
    const int n = node & (N - 1);
    const float* xb = x + (size_t)b * CIN * N + n;

    float acc[H];
#pragma unroll
    for (int h = 0; h < H; ++h) acc[h] = sb1[h];
#pragma unroll
    for (int c = 0; c < CIN; ++c) {
        float xv = xb[(size_t)c * N];         // coalesced across threads
#pragma unroll
        for (int h = 0; h < H; ++h) acc[h] = fmaf(xv, sW1[h * CIN + c], acc[h]);
    }
    const float gw = grid_weight[node];

    float4* dst = (float4*)(hh + (size_t)node * H);
#pragma unroll
    for (int i = 0; i < H / 4; ++i) {
        float4 v;
        v.x = acc[4 * i + 0] * gw * scoef[4 * i + 0];
        v.y = acc[4 * i + 1] * gw * scoef[4 * i + 1];
        v.z = acc[4 * i + 2] * gw * scoef[4 * i + 2];
        v.w = acc[4 * i + 3] * gw * scoef[4 * i + 3];
        dst[i] = v;
    }
}

// ---------------------------------------------------------------------------
// CSR build: histogram -> hierarchical exclusive scan -> scatter src by dst
// ---------------------------------------------------------------------------
__global__ __launch_bounds__(256) void k_hist(const int* __restrict__ edst,
                                              int* __restrict__ counts)
{
    const int e = blockIdx.x * 256 + threadIdx.x;      // [0, E)
    const int b = e >> 19;                             // e / (N*K)
    atomicAdd(&counts[edst[e] + b * N], 1);
}

__global__ __launch_bounds__(256) void k_bsum(const int* __restrict__ counts,
                                              int* __restrict__ bsum)
{
    __shared__ int red[256];
    const int tid = threadIdx.x;
    red[tid] = counts[blockIdx.x * 256 + tid];
    __syncthreads();
    for (int s = 128; s > 0; s >>= 1) {
        if (tid < s) red[tid] += red[tid + s];
        __syncthreads();
    }
    if (tid == 0) bsum[blockIdx.x] = red[0];
}

__global__ __launch_bounds__(512) void k_bscan(int* __restrict__ bsum)
{
    __shared__ int sc[512];
    const int tid = threadIdx.x;
    const int mine = bsum[tid];
    sc[tid] = mine;
    __syncthreads();
    for (int off = 1; off < 512; off <<= 1) {
        int v = (tid >= off) ? sc[tid - off] : 0;
        __syncthreads();
        sc[tid] += v;
        __syncthreads();
    }
    bsum[tid] = sc[tid] - mine;   // exclusive
}

__global__ __launch_bounds__(256) void k_offsets(const int* __restrict__ counts,
                                                 const int* __restrict__ bsum,
                                                 int* __restrict__ offsets,
                                                 int* __restrict__ cursor)
{
    __shared__ int sc[256];
    const int tid = threadIdx.x;
    const int i = blockIdx.x * 256 + tid;
    const int mine = counts[i];
    sc[tid] = mine;
    __syncthreads();
    for (int off = 1; off < 256; off <<= 1) {
        int v = (tid >= off) ? sc[tid - off] : 0;
        __syncthreads();
        sc[tid] += v;
        __syncthreads();
    }
    const int excl = sc[tid] - mine + bsum[blockIdx.x];
    offsets[i] = excl;
    cursor[i]  = excl;
}

__global__ __launch_bounds__(256) void k_scatter(const int* __restrict__ esrc,
                                                 const int* __restrict__ edst,
                                                 int* __restrict__ cursor,
                                                 int* __restrict__ src_sorted)
{
    const int e = blockIdx.x * 256 + threadIdx.x;      // [0, E)
    const int b = e >> 19;
    const int boff = b * N;
    const int s = esrc[e] + boff;
    const int d = edst[e] + boff;
    const int pos = atomicAdd(&cursor[d], 1);
    src_sorted[pos] = s;
}

// ---------------------------------------------------------------------------
// Kernel 3: gather + fc2 + transpose, no f32 atomics.
// Half-wave (32 lanes) per dst node, lane h owns channel h.
// Block = 256 threads = 8 subgroups; processes 64 consecutive nodes in 8
// rounds; outputs staged in LDS then written coalesced (transposed).
// ---------------------------------------------------------------------------
__global__ __launch_bounds__(256) void k_gather(const float* __restrict__ grid,
                                                const float* __restrict__ baseweight,
                                                const float* __restrict__ hh,
                                                const int* __restrict__ src_sorted,
                                                const int* __restrict__ offsets,
                                                const int* __restrict__ counts,
                                                const float* __restrict__ W2,
                                                const float* __restrict__ b2,
                                                float* __restrict__ out)
{
    __shared__ float sW2[COUT][H + 1];      // padded: conflict-free dot
    __shared__ float sb2[COUT];
    __shared__ float sbw[H];
    __shared__ float tmp[8][H + 1];         // per-subgroup acc row (intra-wave)
    __shared__ float stage[64][COUT + 1];   // 64 nodes x 32 outs

    const int tid = threadIdx.x;
    for (int i = tid; i < COUT * H; i += 256) sW2[i >> 5][i & 31] = W2[i];
    if (tid < COUT) sb2[tid] = b2[tid];
    if (tid < H)    sbw[tid] = baseweight[tid];
    __syncthreads();

    const int g    = tid >> 5;        // subgroup 0..7
    const int lane = tid & 31;        // channel
    const int n0   = blockIdx.x * 64; // first node of block (same batch: 32768%64==0)
    const float bwl = sbw[lane];

#pragma unroll
    for (int r = 0; r < 8; ++r) {
        const int nl = g * 8 + r;             // local node 0..63
        const int d  = n0 + nl;
        const int off = offsets[d];
        const int cnt = counts[d];
        const float gx = grid[d * 3 + 0];
        const float gy = grid[d * 3 + 1];
        const float gz = grid[d * 3 + 2];

        float acc = 0.0f;
        for (int i = 0; i < cnt; ++i) {
            const int s = src_sorted[off + i];          // uniform per half-wave
            const float dx = grid[s * 3 + 0] - gx;
            const float dy = grid[s * 3 + 1] - gy;
            const float dz = grid[s * 3 + 2] - gz;
            const float d2 = dx * dx + dy * dy + dz * dz;
            acc = fmaf(__expf(-bwl * d2), hh[(size_t)s * H + lane], acc);
        }

        // fc2 for this node (intra-wave LDS handoff; lockstep => no barrier)
        tmp[g][lane] = acc;
        float o_val = sb2[lane];
#pragma unroll
        for (int h = 0; h < H; ++h)
            o_val = fmaf(tmp[g][h], sW2[lane][h], o_val);   // tmp bcast; sW2 padded
        stage[nl][lane] = o_val;
    }
    __syncthreads();

    // coalesced transposed write: out[b, o, n0..n0+63]
    const int b = n0 >> 15;
    const int nb = n0 & (N - 1);
    float* ob = out + (size_t)b * COUT * N + nb;
#pragma unroll
    for (int i = 0; i < 8; ++i) {
        const int flat = i * 256 + tid;
        const int o = flat >> 6;          // channel
        const int j = flat & 63;          // node offset
        ob[(size_t)o * N + j] = stage[j][o];
    }
}

// ---------------------------------------------------------------------------
extern "C" void kernel_launch(void* const* d_in, const int* in_sizes, int n_in,
                              void* d_out, int out_size, void* d_ws, size_t ws_size,
                              hipStream_t stream)
{
    const float* x    = (const float*)d_in[0];
    const float* grid = (const float*)d_in[1];
    const float* gw   = (const float*)d_in[2];
    const int*   es   = (const int*)d_in[3];
    const int*   ed   = (const int*)d_in[4];
    const float* W1   = (const float*)d_in[5];
    const float* b1   = (const float*)d_in[6];
    const float* W2   = (const float*)d_in[7];
    const float* b2   = (const float*)d_in[8];
    const float* bw   = (const float*)d_in[9];
    float* out = (float*)d_out;

    // workspace layout (bytes): hh 16M | src_sorted 8M | counts .5M | offsets .5M | cursor .5M | bsum 2K
    char* w = (char*)d_ws;
    float* hh         = (float*)(w);
    int*   src_sorted = (int*)(w + (size_t)NODES * H * 4);
    int*   counts     = (int*)(w + (size_t)NODES * H * 4 + (size_t)E * 4);
    int*   offsets    = counts + NODES;
    int*   cursor     = offsets + NODES;
    int*   bsum       = cursor + NODES;

    hipMemsetAsync(counts, 0, (size_t)NODES * sizeof(int), stream);

    k_fc1<<<NODES / 256, 256, 0, stream>>>(x, gw, W1, b1, bw, hh);
    k_hist<<<E / 256, 256, 0, stream>>>(ed, counts);
    k_bsum<<<NBLK, 256, 0, stream>>>(counts, bsum);        // 512 blocks (bugfix)
    k_bscan<<<1, 512, 0, stream>>>(bsum);
    k_offsets<<<NBLK, 256, 0, stream>>>(counts, bsum, offsets, cursor);
    k_scatter<<<E / 256, 256, 0, stream>>>(es, ed, cursor, src_sorted);
    k_gather<<<NODES / 64, 256, 0, stream>>>(grid, bw, hh, src_sorted, offsets,
                                             counts, W2, b2, out);
}

// Round 5
// 410.493 us; speedup vs baseline: 1.2995x; 1.2995x over previous
//
#include <hip/hip_runtime.h>
#include <math.h>

// Problem constants (match reference)
constexpr int B    = 4;
constexpr int N    = 32768;   // 2^15
constexpr int K    = 16;
constexpr int CIN  = 32;
constexpr int H    = 32;
constexpr int COUT = 32;
constexpr int NODES = B * N;          // 131072 = 512*256
constexpr int E      = B * N * K;     // 2097152 edges
constexpr int NBLK  = NODES / 256;    // 512

// ---------------------------------------------------------------------------
// Kernel 1: fc1 + fold grid_weight and gaussian normalizer into hh[node][h]
// ---------------------------------------------------------------------------
__global__ __launch_bounds__(256) void k_fc1(const float* __restrict__ x,
                                             const float* __restrict__ grid_weight,
                                             const float* __restrict__ W1,
                                             const float* __restrict__ b1,
                                             const float* __restrict__ baseweight,
                                             float* __restrict__ hh)
{
    __shared__ float sW1[H * CIN];
    __shared__ float sb1[H];
    __shared__ float scoef[H];
    const int tid = threadIdx.x;
    for (int i = tid; i < H * CIN; i += 256) sW1[i] = W1[i];
    if (tid < H) {
        sb1[tid] = b1[tid];
        float t = baseweight[tid] * (float)(1.0 / M_PI);
        scoef[tid] = t * sqrtf(t);           // (bw/pi)^1.5
    }
    __syncthreads();

    const int node = blockIdx.x * 256 + tid;
    const int b = node >> 15;
    const int n = node & (N - 1);
    const float* xb = x + (size_t)b * CIN * N + n;

    float acc[H];
#pragma unroll
    for (int h = 0; h < H; ++h) acc[h] = sb1[h];
#pragma unroll
    for (int c = 0; c < CIN; ++c) {
        float xv = xb[(size_t)c * N];
#pragma unroll
        for (int h = 0; h < H; ++h) acc[h] = fmaf(xv, sW1[h * CIN + c], acc[h]);
    }
    const float gw = grid_weight[node];

    float4* dst = (float4*)(hh + (size_t)node * H);
#pragma unroll
    for (int i = 0; i < H / 4; ++i) {
        float4 v;
        v.x = acc[4 * i + 0] * gw * scoef[4 * i + 0];
        v.y = acc[4 * i + 1] * gw * scoef[4 * i + 1];
        v.z = acc[4 * i + 2] * gw * scoef[4 * i + 2];
        v.w = acc[4 * i + 3] * gw * scoef[4 * i + 3];
        dst[i] = v;
    }
}

// ---------------------------------------------------------------------------
// CSR build: histogram -> hierarchical exclusive scan -> scatter src by dst
// ---------------------------------------------------------------------------
__global__ __launch_bounds__(256) void k_hist(const int* __restrict__ edst,
                                              int* __restrict__ counts)
{
    const int e = blockIdx.x * 256 + threadIdx.x;
    const int b = e >> 19;
    atomicAdd(&counts[edst[e] + b * N], 1);
}

__global__ __launch_bounds__(256) void k_bsum(const int* __restrict__ counts,
                                              int* __restrict__ bsum)
{
    __shared__ int red[256];
    const int tid = threadIdx.x;
    red[tid] = counts[blockIdx.x * 256 + tid];
    __syncthreads();
    for (int s = 128; s > 0; s >>= 1) {
        if (tid < s) red[tid] += red[tid + s];
        __syncthreads();
    }
    if (tid == 0) bsum[blockIdx.x] = red[0];
}

__global__ __launch_bounds__(512) void k_bscan(int* __restrict__ bsum)
{
    __shared__ int sc[512];
    const int tid = threadIdx.x;
    const int mine = bsum[tid];
    sc[tid] = mine;
    __syncthreads();
    for (int off = 1; off < 512; off <<= 1) {
        int v = (tid >= off) ? sc[tid - off] : 0;
        __syncthreads();
        sc[tid] += v;
        __syncthreads();
    }
    bsum[tid] = sc[tid] - mine;   // exclusive
}

__global__ __launch_bounds__(256) void k_offsets(const int* __restrict__ counts,
                                                 const int* __restrict__ bsum,
                                                 int* __restrict__ offsets,
                                                 int* __restrict__ cursor)
{
    __shared__ int sc[256];
    const int tid = threadIdx.x;
    const int i = blockIdx.x * 256 + tid;
    const int mine = counts[i];
    sc[tid] = mine;
    __syncthreads();
    for (int off = 1; off < 256; off <<= 1) {
        int v = (tid >= off) ? sc[tid - off] : 0;
        __syncthreads();
        sc[tid] += v;
        __syncthreads();
    }
    const int excl = sc[tid] - mine + bsum[blockIdx.x];
    offsets[i] = excl;
    cursor[i]  = excl;
}

__global__ __launch_bounds__(256) void k_scatter(const int* __restrict__ esrc,
                                                 const int* __restrict__ edst,
                                                 int* __restrict__ cursor,
                                                 int* __restrict__ src_sorted)
{
    const int e = blockIdx.x * 256 + threadIdx.x;
    const int b = e >> 19;
    const int boff = b * N;
    const int s = esrc[e] + boff;
    const int d = edst[e] + boff;
    const int pos = atomicAdd(&cursor[d], 1);
    src_sorted[pos] = s;
}

// ---------------------------------------------------------------------------
// Gather + fc2 + transpose, MLP-restructured:
//  phase 1: lane i loads edge i's src & computes d2 (parallel across lanes)
//  phase 2: shfl-broadcast (s,d2) from registers; 4-way unrolled hh loads
// Half-wave (32 lanes) per dst node, lane = channel.
// ---------------------------------------------------------------------------
__global__ __launch_bounds__(256) void k_gather(const float* __restrict__ grid,
                                                const float* __restrict__ baseweight,
                                                const float* __restrict__ hh,
                                                const int* __restrict__ src_sorted,
                                                const int* __restrict__ offsets,
                                                const int* __restrict__ counts,
                                                const float* __restrict__ W2,
                                                const float* __restrict__ b2,
                                                float* __restrict__ out)
{
    __shared__ float sW2[COUT][H + 1];
    __shared__ float sb2[COUT];
    __shared__ float sbw[H];
    __shared__ float tmp[8][H + 1];
    __shared__ float stage[64][COUT + 1];

    const int tid = threadIdx.x;
    for (int i = tid; i < COUT * H; i += 256) sW2[i >> 5][i & 31] = W2[i];
    if (tid < COUT) sb2[tid] = b2[tid];
    if (tid < H)    sbw[tid] = baseweight[tid];
    __syncthreads();

    const int g    = tid >> 5;        // subgroup 0..7 (32-lane aligned)
    const int lane = tid & 31;        // channel
    const int n0   = blockIdx.x * 64;
    const float bwl = sbw[lane];

#pragma unroll
    for (int r = 0; r < 8; ++r) {
        const int nl = g * 8 + r;
        const int d  = n0 + nl;
        const int off = offsets[d];
        const int cnt = counts[d];
        const float gx = grid[d * 3 + 0];
        const float gy = grid[d * 3 + 1];
        const float gz = grid[d * 3 + 2];

        float acc = 0.0f;
        for (int base = 0; base < cnt; base += 32) {
            const int m = min(32, cnt - base);

            // phase 1: parallel per-lane edge fetch + d2
            int   s_l  = 0;
            float d2_l = 0.0f;
            if (lane < m) {
                s_l = src_sorted[off + base + lane];      // coalesced
                const float dx = grid[s_l * 3 + 0] - gx;  // parallel gathers
                const float dy = grid[s_l * 3 + 1] - gy;
                const float dz = grid[s_l * 3 + 2] - gz;
                d2_l = dx * dx + dy * dy + dz * dz;
            }

            // phase 2: broadcast from registers, 4-deep independent hh loads
            int i = 0;
            for (; i + 4 <= m; i += 4) {
                const int s0 = __shfl(s_l, i + 0, 32);
                const int s1 = __shfl(s_l, i + 1, 32);
                const int s2 = __shfl(s_l, i + 2, 32);
                const int s3 = __shfl(s_l, i + 3, 32);
                const float w0 = __shfl(d2_l, i + 0, 32);
                const float w1 = __shfl(d2_l, i + 1, 32);
                const float w2 = __shfl(d2_l, i + 2, 32);
                const float w3 = __shfl(d2_l, i + 3, 32);
                const float h0 = hh[(size_t)s0 * H + lane];
                const float h1 = hh[(size_t)s1 * H + lane];
                const float h2 = hh[(size_t)s2 * H + lane];
                const float h3 = hh[(size_t)s3 * H + lane];
                acc = fmaf(__expf(-bwl * w0), h0, acc);
                acc = fmaf(__expf(-bwl * w1), h1, acc);
                acc = fmaf(__expf(-bwl * w2), h2, acc);
                acc = fmaf(__expf(-bwl * w3), h3, acc);
            }
            for (; i < m; ++i) {
                const int   s = __shfl(s_l, i, 32);
                const float w = __shfl(d2_l, i, 32);
                acc = fmaf(__expf(-bwl * w), hh[(size_t)s * H + lane], acc);
            }
        }

        // fc2 for this node (intra-wave lockstep; no barrier needed)
        tmp[g][lane] = acc;
        float o_val = sb2[lane];
#pragma unroll
        for (int h = 0; h < H; ++h)
            o_val = fmaf(tmp[g][h], sW2[lane][h], o_val);
        stage[nl][lane] = o_val;
    }
    __syncthreads();

    // coalesced transposed write: out[b, o, n0..n0+63]
    const int b = n0 >> 15;
    const int nb = n0 & (N - 1);
    float* ob = out + (size_t)b * COUT * N + nb;
#pragma unroll
    for (int i = 0; i < 8; ++i) {
        const int flat = i * 256 + tid;
        const int o = flat >> 6;
        const int j = flat & 63;
        ob[(size_t)o * N + j] = stage[j][o];
    }
}

// ---------------------------------------------------------------------------
extern "C" void kernel_launch(void* const* d_in, const int* in_sizes, int n_in,
                              void* d_out, int out_size, void* d_ws, size_t ws_size,
                              hipStream_t stream)
{
    const float* x    = (const float*)d_in[0];
    const float* grid = (const float*)d_in[1];
    const float* gw   = (const float*)d_in[2];
    const int*   es   = (const int*)d_in[3];
    const int*   ed   = (const int*)d_in[4];
    const float* W1   = (const float*)d_in[5];
    const float* b1   = (const float*)d_in[6];
    const float* W2   = (const float*)d_in[7];
    const float* b2   = (const float*)d_in[8];
    const float* bw   = (const float*)d_in[9];
    float* out = (float*)d_out;

    // workspace: hh 16M | src_sorted 8M | counts .5M | offsets .5M | cursor .5M | bsum 2K
    char* w = (char*)d_ws;
    float* hh         = (float*)(w);
    int*   src_sorted = (int*)(w + (size_t)NODES * H * 4);
    int*   counts     = (int*)(w + (size_t)NODES * H * 4 + (size_t)E * 4);
    int*   offsets    = counts + NODES;
    int*   cursor     = offsets + NODES;
    int*   bsum       = cursor + NODES;

    hipMemsetAsync(counts, 0, (size_t)NODES * sizeof(int), stream);

    k_fc1<<<NODES / 256, 256, 0, stream>>>(x, gw, W1, b1, bw, hh);
    k_hist<<<E / 256, 256, 0, stream>>>(ed, counts);
    k_bsum<<<NBLK, 256, 0, stream>>>(counts, bsum);
    k_bscan<<<1, 512, 0, stream>>>(bsum);
    k_offsets<<<NBLK, 256, 0, stream>>>(counts, bsum, offsets, cursor);
    k_scatter<<<E / 256, 256, 0, stream>>>(es, ed, cursor, src_sorted);
    k_gather<<<NODES / 64, 256, 0, stream>>>(grid, bw, hh, src_sorted, offsets,
                                             counts, W2, b2, out);
}

// Round 6
// 291.115 us; speedup vs baseline: 1.8324x; 1.4101x over previous
//
#include <hip/hip_runtime.h>
#include <math.h>

// Problem constants (match reference)
constexpr int B    = 4;
constexpr int N    = 32768;   // 2^15
constexpr int K    = 16;
constexpr int CIN  = 32;
constexpr int H    = 32;
constexpr int COUT = 32;
constexpr int NODES = B * N;          // 131072 = 512*256
constexpr int E      = B * N * K;     // 2097152 edges
constexpr int NBLK  = NODES / 256;    // 512

// ---------------------------------------------------------------------------
// Kernel 1: fc1 + fold grid_weight and gaussian normalizer into hh[node][h]
// ---------------------------------------------------------------------------
__global__ __launch_bounds__(256) void k_fc1(const float* __restrict__ x,
                                             const float* __restrict__ grid_weight,
                                             const float* __restrict__ W1,
                                             const float* __restrict__ b1,
                                             const float* __restrict__ baseweight,
                                             float* __restrict__ hh)
{
    __shared__ float sW1[H * CIN];
    __shared__ float sb1[H];
    __shared__ float scoef[H];
    const int tid = threadIdx.x;
    for (int i = tid; i < H * CIN; i += 256) sW1[i] = W1[i];
    if (tid < H) {
        sb1[tid] = b1[tid];
        float t = baseweight[tid] * (float)(1.0 / M_PI);
        scoef[tid] = t * sqrtf(t);           // (bw/pi)^1.5
    }
    __syncthreads();

    const int node = blockIdx.x * 256 + tid;
    const int b = node >> 15;
    const int n = node & (N - 1);
    const float* xb = x + (size_t)b * CIN * N + n;

    float acc[H];
#pragma unroll
    for (int h = 0; h < H; ++h) acc[h] = sb1[h];
#pragma unroll
    for (int c = 0; c < CIN; ++c) {
        float xv = xb[(size_t)c * N];
#pragma unroll
        for (int h = 0; h < H; ++h) acc[h] = fmaf(xv, sW1[h * CIN + c], acc[h]);
    }
    const float gw = grid_weight[node];

    float4* dst = (float4*)(hh + (size_t)node * H);
#pragma unroll
    for (int i = 0; i < H / 4; ++i) {
        float4 v;
        v.x = acc[4 * i + 0] * gw * scoef[4 * i + 0];
        v.y = acc[4 * i + 1] * gw * scoef[4 * i + 1];
        v.z = acc[4 * i + 2] * gw * scoef[4 * i + 2];
        v.w = acc[4 * i + 3] * gw * scoef[4 * i + 3];
        dst[i] = v;
    }
}

// ---------------------------------------------------------------------------
// CSR build
// ---------------------------------------------------------------------------
// hist + per-edge rank (the atomicAdd return value IS the rank — free)
__global__ __launch_bounds__(256) void k_hist_pos(const int* __restrict__ edst,
                                                  int* __restrict__ counts,
                                                  int* __restrict__ pos)
{
    const int e = blockIdx.x * 256 + threadIdx.x;
    const int b = e >> 19;
    pos[e] = atomicAdd(&counts[edst[e] + b * N], 1);   // pos write coalesced
}

__global__ __launch_bounds__(256) void k_hist(const int* __restrict__ edst,
                                              int* __restrict__ counts)
{
    const int e = blockIdx.x * 256 + threadIdx.x;
    const int b = e >> 19;
    atomicAdd(&counts[edst[e] + b * N], 1);
}

__global__ __launch_bounds__(256) void k_bsum(const int* __restrict__ counts,
                                              int* __restrict__ bsum)
{
    __shared__ int red[256];
    const int tid = threadIdx.x;
    red[tid] = counts[blockIdx.x * 256 + tid];
    __syncthreads();
    for (int s = 128; s > 0; s >>= 1) {
        if (tid < s) red[tid] += red[tid + s];
        __syncthreads();
    }
    if (tid == 0) bsum[blockIdx.x] = red[0];
}

__global__ __launch_bounds__(512) void k_bscan(int* __restrict__ bsum)
{
    __shared__ int sc[512];
    const int tid = threadIdx.x;
    const int mine = bsum[tid];
    sc[tid] = mine;
    __syncthreads();
    for (int off = 1; off < 512; off <<= 1) {
        int v = (tid >= off) ? sc[tid - off] : 0;
        __syncthreads();
        sc[tid] += v;
        __syncthreads();
    }
    bsum[tid] = sc[tid] - mine;   // exclusive
}

__global__ __launch_bounds__(256) void k_offsets(const int* __restrict__ counts,
                                                 const int* __restrict__ bsum,
                                                 int* __restrict__ offsets,
                                                 int* __restrict__ cursor)
{
    __shared__ int sc[256];
    const int tid = threadIdx.x;
    const int i = blockIdx.x * 256 + tid;
    const int mine = counts[i];
    sc[tid] = mine;
    __syncthreads();
    for (int off = 1; off < 256; off <<= 1) {
        int v = (tid >= off) ? sc[tid - off] : 0;
        __syncthreads();
        sc[tid] += v;
        __syncthreads();
    }
    const int excl = sc[tid] - mine + bsum[blockIdx.x];
    offsets[i] = excl;
    cursor[i]  = excl;
}

// atomic-free scatter: rank precomputed, offsets table is read-only (L2-hit)
__global__ __launch_bounds__(256) void k_scatter_nf(const int* __restrict__ esrc,
                                                    const int* __restrict__ edst,
                                                    const int* __restrict__ pos,
                                                    const int* __restrict__ offsets,
                                                    int* __restrict__ src_sorted)
{
    const int e = blockIdx.x * 256 + threadIdx.x;
    const int b = e >> 19;
    const int boff = b * N;
    const int d = edst[e] + boff;
    src_sorted[offsets[d] + pos[e]] = esrc[e] + boff;
}

// fallback (atomic) scatter — used only if workspace is too small
__global__ __launch_bounds__(256) void k_scatter(const int* __restrict__ esrc,
                                                 const int* __restrict__ edst,
                                                 int* __restrict__ cursor,
                                                 int* __restrict__ src_sorted)
{
    const int e = blockIdx.x * 256 + threadIdx.x;
    const int b = e >> 19;
    const int boff = b * N;
    const int s = esrc[e] + boff;
    const int d = edst[e] + boff;
    const int posn = atomicAdd(&cursor[d], 1);
    src_sorted[posn] = s;
}

// ---------------------------------------------------------------------------
// Gather + fc2 + transpose (unchanged from round 5)
// ---------------------------------------------------------------------------
__global__ __launch_bounds__(256) void k_gather(const float* __restrict__ grid,
                                                const float* __restrict__ baseweight,
                                                const float* __restrict__ hh,
                                                const int* __restrict__ src_sorted,
                                                const int* __restrict__ offsets,
                                                const int* __restrict__ counts,
                                                const float* __restrict__ W2,
                                                const float* __restrict__ b2,
                                                float* __restrict__ out)
{
    __shared__ float sW2[COUT][H + 1];
    __shared__ float sb2[COUT];
    __shared__ float sbw[H];
    __shared__ float tmp[8][H + 1];
    __shared__ float stage[64][COUT + 1];

    const int tid = threadIdx.x;
    for (int i = tid; i < COUT * H; i += 256) sW2[i >> 5][i & 31] = W2[i];
    if (tid < COUT) sb2[tid] = b2[tid];
    if (tid < H)    sbw[tid] = baseweight[tid];
    __syncthreads();

    const int g    = tid >> 5;
    const int lane = tid & 31;
    const int n0   = blockIdx.x * 64;
    const float bwl = sbw[lane];

#pragma unroll
    for (int r = 0; r < 8; ++r) {
        const int nl = g * 8 + r;
        const int d  = n0 + nl;
        const int off = offsets[d];
        const int cnt = counts[d];
        const float gx = grid[d * 3 + 0];
        const float gy = grid[d * 3 + 1];
        const float gz = grid[d * 3 + 2];

        float acc = 0.0f;
        for (int base = 0; base < cnt; base += 32) {
            const int m = min(32, cnt - base);

            int   s_l  = 0;
            float d2_l = 0.0f;
            if (lane < m) {
                s_l = src_sorted[off + base + lane];
                const float dx = grid[s_l * 3 + 0] - gx;
                const float dy = grid[s_l * 3 + 1] - gy;
                const float dz = grid[s_l * 3 + 2] - gz;
                d2_l = dx * dx + dy * dy + dz * dz;
            }

            int i = 0;
            for (; i + 4 <= m; i += 4) {
                const int s0 = __shfl(s_l, i + 0, 32);
                const int s1 = __shfl(s_l, i + 1, 32);
                const int s2 = __shfl(s_l, i + 2, 32);
                const int s3 = __shfl(s_l, i + 3, 32);
                const float w0 = __shfl(d2_l, i + 0, 32);
                const float w1 = __shfl(d2_l, i + 1, 32);
                const float w2 = __shfl(d2_l, i + 2, 32);
                const float w3 = __shfl(d2_l, i + 3, 32);
                const float h0 = hh[(size_t)s0 * H + lane];
                const float h1 = hh[(size_t)s1 * H + lane];
                const float h2 = hh[(size_t)s2 * H + lane];
                const float h3 = hh[(size_t)s3 * H + lane];
                acc = fmaf(__expf(-bwl * w0), h0, acc);
                acc = fmaf(__expf(-bwl * w1), h1, acc);
                acc = fmaf(__expf(-bwl * w2), h2, acc);
                acc = fmaf(__expf(-bwl * w3), h3, acc);
            }
            for (; i < m; ++i) {
                const int   s = __shfl(s_l, i, 32);
                const float w = __shfl(d2_l, i, 32);
                acc = fmaf(__expf(-bwl * w), hh[(size_t)s * H + lane], acc);
            }
        }

        tmp[g][lane] = acc;
        float o_val = sb2[lane];
#pragma unroll
        for (int h = 0; h < H; ++h)
            o_val = fmaf(tmp[g][h], sW2[lane][h], o_val);
        stage[nl][lane] = o_val;
    }
    __syncthreads();

    const int b = n0 >> 15;
    const int nb = n0 & (N - 1);
    float* ob = out + (size_t)b * COUT * N + nb;
#pragma unroll
    for (int i = 0; i < 8; ++i) {
        const int flat = i * 256 + tid;
        const int o = flat >> 6;
        const int j = flat & 63;
        ob[(size_t)o * N + j] = stage[j][o];
    }
}

// ---------------------------------------------------------------------------
extern "C" void kernel_launch(void* const* d_in, const int* in_sizes, int n_in,
                              void* d_out, int out_size, void* d_ws, size_t ws_size,
                              hipStream_t stream)
{
    const float* x    = (const float*)d_in[0];
    const float* grid = (const float*)d_in[1];
    const float* gw   = (const float*)d_in[2];
    const int*   es   = (const int*)d_in[3];
    const int*   ed   = (const int*)d_in[4];
    const float* W1   = (const float*)d_in[5];
    const float* b1   = (const float*)d_in[6];
    const float* W2   = (const float*)d_in[7];
    const float* b2   = (const float*)d_in[8];
    const float* bw   = (const float*)d_in[9];
    float* out = (float*)d_out;

    // New layout: hh 16M | src_sorted 8M | pos 8M | counts .5 | offsets .5 | cursor .5 | bsum 2K
    const size_t need_new = (size_t)NODES * H * 4 + (size_t)E * 4 * 2
                          + (size_t)NODES * 4 * 3 + 2048;
    char* w = (char*)d_ws;
    float* hh         = (float*)(w);
    int*   src_sorted = (int*)(w + (size_t)NODES * H * 4);

    if (ws_size >= need_new) {
        int* pos     = src_sorted + E;
        int* counts  = pos + E;
        int* offsets = counts + NODES;
        int* cursor  = offsets + NODES;
        int* bsum    = cursor + NODES;

        hipMemsetAsync(counts, 0, (size_t)NODES * sizeof(int), stream);
        k_fc1<<<NODES / 256, 256, 0, stream>>>(x, gw, W1, b1, bw, hh);
        k_hist_pos<<<E / 256, 256, 0, stream>>>(ed, counts, pos);
        k_bsum<<<NBLK, 256, 0, stream>>>(counts, bsum);
        k_bscan<<<1, 512, 0, stream>>>(bsum);
        k_offsets<<<NBLK, 256, 0, stream>>>(counts, bsum, offsets, cursor);
        k_scatter_nf<<<E / 256, 256, 0, stream>>>(es, ed, pos, offsets, src_sorted);
        k_gather<<<NODES / 64, 256, 0, stream>>>(grid, bw, hh, src_sorted, offsets,
                                                 counts, W2, b2, out);
    } else {
        // fallback: round-5 layout with atomic scatter
        int* counts  = src_sorted + E;
        int* offsets = counts + NODES;
        int* cursor  = offsets + NODES;
        int* bsum    = cursor + NODES;

        hipMemsetAsync(counts, 0, (size_t)NODES * sizeof(int), stream);
        k_fc1<<<NODES / 256, 256, 0, stream>>>(x, gw, W1, b1, bw, hh);
        k_hist<<<E / 256, 256, 0, stream>>>(ed, counts);
        k_bsum<<<NBLK, 256, 0, stream>>>(counts, bsum);
        k_bscan<<<1, 512, 0, stream>>>(bsum);
        k_offsets<<<NBLK, 256, 0, stream>>>(counts, bsum, offsets, cursor);
        k_scatter<<<E / 256, 256, 0, stream>>>(es, ed, cursor, src_sorted);
        k_gather<<<NODES / 64, 256, 0, stream>>>(grid, bw, hh, src_sorted, offsets,
                                                 counts, W2, b2, out);
    }
}